// Round 5
// baseline (685.194 us; speedup 1.0000x reference)
//
#include <hip/hip_runtime.h>
#include <hip/hip_bf16.h>
#include <stdint.h>

typedef unsigned short u16;
typedef __bf16 bf16_t;
typedef bf16_t bf16x8 __attribute__((ext_vector_type(8)));
typedef u16    u16x8  __attribute__((ext_vector_type(8)));
typedef float  f32x4  __attribute__((ext_vector_type(4)));

#define BSZ    256
#define NATOMS 128
#define INF    128
#define HH     256
#define H3     768
#define MAXV   6
#define OUTF   256
#define KFC    (HH * MAXV)      // 1536
#define PLANE  8388608          // u16 elems per xp2 gate plane: 16*128*8*64*8

__device__ __forceinline__ u16 f2bf(float f) {
  union { float f; unsigned u; } v; v.f = f;
  unsigned u = v.u;
  unsigned r = (u + 0x7FFFu + ((u >> 16) & 1u)) >> 16;  // RNE
  return (u16)r;
}
__device__ __forceinline__ float bf2f(u16 h) {
  union { unsigned u; float f; } v; v.u = ((unsigned)h) << 16;
  return v.f;
}
__device__ __forceinline__ f32x4 mfma_bf16(u16x8 a, u16x8 b, f32x4 c) {
  return __builtin_amdgcn_mfma_f32_16x16x32_bf16(
      __builtin_bit_cast(bf16x8, a), __builtin_bit_cast(bf16x8, b), c, 0, 0, 0);
}

// ---------------- prep: W_hh and W_fc fp32 -> bf16 ----------------
__global__ void k_prep(const float* __restrict__ whh, u16* __restrict__ whho,
                       const float* __restrict__ wfc, u16* __restrict__ wfco) {
  int i = blockIdx.x * 256 + threadIdx.x;
  if (i < H3 * HH) whho[i] = f2bf(whh[i]);
  if (i < OUTF * KFC) wfco[i] = f2bf(wfc[i]);
}

// ---------------- stage 1: xp2 = x @ W_ih^T + bih (+bhh for r,z gates) ------
// Output layout (3 gate planes, matched to k_gru's lane/wave mapping):
//   plane g, u16 index: ((bb*128 + t)*8 + w)*512 + L*8 + p*4 + r
//   where b=bb*16+mb, L=(mb>>2)*16+c, r=mb&3, n = g*256 + w*32 + p*16 + c.
// => per (thread,step) in k_gru the 8 needed u16 are one contiguous 16B load.
__global__ __launch_bounds__(256) void k_xproj(const float* __restrict__ X,
                                               const float* __restrict__ W,
                                               const float* __restrict__ bias,
                                               const float* __restrict__ bhh,
                                               u16* __restrict__ out) {
  __shared__ __align__(16) u16 As[64][40];
  __shared__ __align__(16) u16 Bs[64][40];
  const int m0 = blockIdx.x * 64, n0 = blockIdx.y * 64;
  const int tid = threadIdx.x, lane = tid & 63, wid = tid >> 6;
  const int wm = (wid & 1) * 32, wn = (wid >> 1) * 32;
  const int lrow = tid >> 2, lcol = (tid & 3) * 8;
  const f32x4 zero = {0.f, 0.f, 0.f, 0.f};
  f32x4 acc[2][2];
#pragma unroll
  for (int mi = 0; mi < 2; mi++)
#pragma unroll
    for (int ni = 0; ni < 2; ni++) acc[mi][ni] = zero;

  for (int kk = 0; kk < INF; kk += 32) {
    const float* ap = X + (size_t)(m0 + lrow) * INF + kk + lcol;
    const float* bp = W + (size_t)(n0 + lrow) * INF + kk + lcol;
    u16x8 av, bv;
#pragma unroll
    for (int j = 0; j < 8; j++) { av[j] = f2bf(ap[j]); bv[j] = f2bf(bp[j]); }
    *(u16x8*)&As[lrow][lcol] = av;
    *(u16x8*)&Bs[lrow][lcol] = bv;
    __syncthreads();
    u16x8 afr[2], bfr[2];
#pragma unroll
    for (int mi = 0; mi < 2; mi++)
      afr[mi] = *(const u16x8*)&As[wm + mi * 16 + (lane & 15)][(lane >> 4) * 8];
#pragma unroll
    for (int ni = 0; ni < 2; ni++)
      bfr[ni] = *(const u16x8*)&Bs[wn + ni * 16 + (lane & 15)][(lane >> 4) * 8];
#pragma unroll
    for (int mi = 0; mi < 2; mi++)
#pragma unroll
      for (int ni = 0; ni < 2; ni++) acc[mi][ni] = mfma_bf16(afr[mi], bfr[ni], acc[mi][ni]);
    __syncthreads();
  }
#pragma unroll
  for (int mi = 0; mi < 2; mi++)
#pragma unroll
    for (int ni = 0; ni < 2; ni++) {
      const int n = n0 + wn + ni * 16 + (lane & 15);
      const int g = n >> 8, i2 = n & 255;
      const int ww = i2 >> 5, ii = i2 & 31, pp = ii >> 4, cc = ii & 15;
      const float badd = bias[n] + (g < 2 ? bhh[n] : 0.f);  // fold bhh into r,z
      u16* plane = out + (size_t)g * PLANE;
#pragma unroll
      for (int r = 0; r < 4; r++) {
        const int m = m0 + wm + mi * 16 + (lane >> 4) * 4 + r;  // m = b*128 + t
        const int b = m >> 7, t = m & 127, bb = b >> 4, mb = b & 15;
        const size_t off = ((size_t)((bb * 128 + t) * 8 + ww) << 9) +
                           ((((mb >> 2) << 4) | cc) << 3) + pp * 4 + (mb & 3);
        plane[off] = f2bf(acc[mi][ni][r] + badd);
      }
    }
}

// ---------------- stage 2: GRU recurrence -----------------------------------
// 16 blocks x 512 thr (8 waves, 2/EU); block owns 16 batches (full M=16).
// Wave w owns W_hh rows {g*256 + w*32 .. +32} for g=r,z,n (192 regs, pinned)
// -> each lane's D-fragments hold matching (hr,hz,hn) => gates in-register.
// xp prefetched one step ahead INTO REGISTERS (R4's global_load_lds staging
// regressed: alias-conservative vmcnt(0) before the xpb reads/barrier put the
// prefetch latency on the critical path twice per step).
__global__ void __attribute__((amdgpu_flat_work_group_size(512, 512),
                               amdgpu_waves_per_eu(2, 2)))
k_gru(const u16* __restrict__ Whh, const float* __restrict__ bhh,
      const u16* __restrict__ xp2, u16* __restrict__ rnn) {
  __shared__ __align__(16) u16 hA[2][16 * 264];       // bf16 h, A-layout, dbuf
  const int tid = threadIdx.x, lane = tid & 63, w = tid >> 6;  // w in [0,8)
  const int c = lane & 15, quad = lane >> 4;
  const int b0 = blockIdx.x * 16;

  for (int i = tid; i < 2 * 16 * 264; i += 512) ((u16*)hA)[i] = 0;

  // W_hh fragments: 6 tiles (g2 = gate*2 + p) x 8 k-frags = 192 regs
  u16x8 wf[6][8];
#pragma unroll
  for (int g2 = 0; g2 < 6; g2++)
#pragma unroll
    for (int kt = 0; kt < 8; kt++) {
      const int n = (g2 >> 1) * 256 + w * 32 + (g2 & 1) * 16 + c;
      wf[g2][kt] = *(const u16x8*)(Whh + (size_t)n * HH + kt * 32 + quad * 8);
    }
#pragma unroll
  for (int g2 = 0; g2 < 6; g2++)
#pragma unroll
    for (int kt = 0; kt < 8; kt++) asm volatile("" : "+v"(wf[g2][kt]));

  const float bhhn0 = bhh[512 + w * 32 + c];
  const float bhhn1 = bhh[512 + w * 32 + 16 + c];
  float hreg[8] = {0.f, 0.f, 0.f, 0.f, 0.f, 0.f, 0.f, 0.f};

  // per-thread xp stream: 8 contiguous u16 per gate plane per step
  const u16* gbase = xp2 + ((size_t)(blockIdx.x * 128) * 8 + w) * 512 + (size_t)lane * 8;
  const unsigned rnnA = (unsigned)((b0 + quad * 4) * (NATOMS * HH) + w * 32 + c);

  // register prefetch of t=0
  u16x8 xgn[3];
#pragma unroll
  for (int g = 0; g < 3; g++) xgn[g] = *(const u16x8*)(gbase + (size_t)g * PLANE);

  __syncthreads();

  const f32x4 zero4 = {0.f, 0.f, 0.f, 0.f};
#pragma unroll 1
  for (int t = 0; t < NATOMS; t++) {
    const u16* hc = hA[t & 1];
    u16* hnx = hA[(t + 1) & 1];

    // consume prefetched xp, immediately issue next step's loads
    u16x8 xg[3];
#pragma unroll
    for (int g = 0; g < 3; g++) xg[g] = xgn[g];
    if (t < NATOMS - 1) {
      const u16* gp = gbase + (size_t)(t + 1) * 4096;
#pragma unroll
      for (int g = 0; g < 3; g++) xgn[g] = *(const u16x8*)(gp + (size_t)g * PLANE);
    }

    // ---- gh = h @ Whh^T: one af per kt feeds all 6 tiles ----
    f32x4 acc[6] = {zero4, zero4, zero4, zero4, zero4, zero4};
#pragma unroll
    for (int kt = 0; kt < 8; kt++) {
      const u16x8 a = *(const u16x8*)&hc[c * 264 + kt * 32 + quad * 8];
      acc[0] = mfma_bf16(a, wf[0][kt], acc[0]);   // r, cols p=0
      acc[3] = mfma_bf16(a, wf[1][kt], acc[3]);   // r, cols p=1
      acc[1] = mfma_bf16(a, wf[2][kt], acc[1]);   // z, p=0
      acc[4] = mfma_bf16(a, wf[3][kt], acc[4]);   // z, p=1
      acc[2] = mfma_bf16(a, wf[4][kt], acc[2]);   // n, p=0
      acc[5] = mfma_bf16(a, wf[5][kt], acc[5]);   // n, p=1
    }

    // ---- gates fully in-register; bih+bhh pre-folded for r,z ----
#pragma unroll
    for (int r_ = 0; r_ < 4; r_++) {
      {  // half p=0
        const float ar = acc[0][r_] + bf2f(xg[0][r_]);
        const float az = acc[1][r_] + bf2f(xg[1][r_]);
        const float hn = acc[2][r_] + bhhn0;
        const float xn = bf2f(xg[2][r_]);
        const float rr = 1.f / (1.f + __expf(-ar));
        const float zz = 1.f / (1.f + __expf(-az));
        const float e  = __expf(2.f * (xn + rr * hn));
        const float nn = 1.f - 2.f / (e + 1.f);
        const float hv = nn + zz * (hreg[r_] - nn);
        hreg[r_] = hv;
        const u16 hb = f2bf(hv);
        hnx[(quad * 4 + r_) * 264 + w * 32 + c] = hb;
        rnn[rnnA + r_ * 32768u + (unsigned)t * 256u] = hb;
      }
      {  // half p=1
        const float ar = acc[3][r_] + bf2f(xg[0][4 + r_]);
        const float az = acc[4][r_] + bf2f(xg[1][4 + r_]);
        const float hn = acc[5][r_] + bhhn1;
        const float xn = bf2f(xg[2][4 + r_]);
        const float rr = 1.f / (1.f + __expf(-ar));
        const float zz = 1.f / (1.f + __expf(-az));
        const float e  = __expf(2.f * (xn + rr * hn));
        const float nn = 1.f - 2.f / (e + 1.f);
        const float hv = nn + zz * (hreg[4 + r_] - nn);
        hreg[4 + r_] = hv;
        const u16 hb = f2bf(hv);
        hnx[(quad * 4 + r_) * 264 + w * 32 + 16 + c] = hb;
        rnn[rnnA + r_ * 32768u + (unsigned)t * 256u + 16u] = hb;
      }
    }
    __syncthreads();
  }
}

// ---------------- stage 3: out = leaky(gather(rnn) @ W_fc^T + b_fc) ---------
__global__ __launch_bounds__(256) void k_fc(const u16* __restrict__ rnn,
                                            const int* __restrict__ bonded,
                                            const u16* __restrict__ W,
                                            const float* __restrict__ bias,
                                            float* __restrict__ out) {
  __shared__ __align__(16) u16 As[64][40];
  __shared__ __align__(16) u16 Bs[64][40];
  const int m0 = blockIdx.x * 64, n0 = blockIdx.y * 64;
  const int tid = threadIdx.x, lane = tid & 63, wid = tid >> 6;
  const int wm = (wid & 1) * 32, wn = (wid >> 1) * 32;
  const int lrow = tid >> 2, lcol = (tid & 3) * 8;
  const int m = m0 + lrow;
  const int b = m >> 7, atom = m & 127;
  const int* bptr = bonded + (size_t)(b * NATOMS + atom) * MAXV;
  const f32x4 zero = {0.f, 0.f, 0.f, 0.f};
  f32x4 acc[2][2];
#pragma unroll
  for (int mi = 0; mi < 2; mi++)
#pragma unroll
    for (int ni = 0; ni < 2; ni++) acc[mi][ni] = zero;

  for (int kk = 0; kk < KFC; kk += 32) {
    int k = kk + lcol;
    int v = k >> 8, kr = k & 255;
    int idx = bptr[v];
    u16x8 av = *(const u16x8*)(rnn + (size_t)(b * NATOMS + idx) * HH + kr);
    u16x8 bv = *(const u16x8*)(W + (size_t)(n0 + lrow) * KFC + k);
    *(u16x8*)&As[lrow][lcol] = av;
    *(u16x8*)&Bs[lrow][lcol] = bv;
    __syncthreads();
    u16x8 afr[2], bfr[2];
#pragma unroll
    for (int mi = 0; mi < 2; mi++)
      afr[mi] = *(const u16x8*)&As[wm + mi * 16 + (lane & 15)][(lane >> 4) * 8];
#pragma unroll
    for (int ni = 0; ni < 2; ni++)
      bfr[ni] = *(const u16x8*)&Bs[wn + ni * 16 + (lane & 15)][(lane >> 4) * 8];
#pragma unroll
    for (int mi = 0; mi < 2; mi++)
#pragma unroll
      for (int ni = 0; ni < 2; ni++) acc[mi][ni] = mfma_bf16(afr[mi], bfr[ni], acc[mi][ni]);
    __syncthreads();
  }
#pragma unroll
  for (int mi = 0; mi < 2; mi++)
#pragma unroll
    for (int ni = 0; ni < 2; ni++) {
      int n = n0 + wn + ni * 16 + (lane & 15);
      float bv = bias[n];
#pragma unroll
      for (int r = 0; r < 4; r++) {
        int mm = m0 + wm + mi * 16 + (lane >> 4) * 4 + r;
        float vv = acc[mi][ni][r] + bv;
        out[(size_t)mm * OUTF + n] = vv >= 0.f ? vv : 0.1f * vv;
      }
    }
}

extern "C" void kernel_launch(void* const* d_in, const int* in_sizes, int n_in,
                              void* d_out, int out_size, void* d_ws, size_t ws_size,
                              hipStream_t stream) {
  const float* x      = (const float*)d_in[0];
  const int*   bonded = (const int*)d_in[1];
  const float* Wih    = (const float*)d_in[2];
  const float* Whh    = (const float*)d_in[3];
  const float* bih    = (const float*)d_in[4];
  const float* bhh    = (const float*)d_in[5];
  const float* Wfc    = (const float*)d_in[6];
  const float* bfc    = (const float*)d_in[7];
  float* out = (float*)d_out;

  char* ws = (char*)d_ws;
  u16* xp2  = (u16*)(ws);                                    // 3*16MB = 50,331,648 B
  u16* rnn  = (u16*)(ws + 50331648);                         // 16,777,216 B
  u16* whhb = (u16*)(ws + 50331648 + 16777216);              //    393,216 B
  u16* wfcb = (u16*)(ws + 50331648 + 16777216 + 393216);     //    786,432 B

  k_prep<<<(OUTF * KFC + 255) / 256, 256, 0, stream>>>(Whh, whhb, Wfc, wfcb);
  k_xproj<<<dim3(512, 12), 256, 0, stream>>>(x, Wih, bih, bhh, xp2);
  k_gru<<<16, 512, 0, stream>>>(whhb, bhh, xp2, rnn);
  k_fc<<<dim3(512, 4), 256, 0, stream>>>(rnn, bonded, wfcb, bfc, out);
}

// Round 6
// 433.235 us; speedup vs baseline: 1.5816x; 1.5816x over previous
//
#include <hip/hip_runtime.h>
#include <hip/hip_bf16.h>
#include <stdint.h>

typedef unsigned short u16;
typedef __bf16 bf16_t;
typedef bf16_t bf16x8 __attribute__((ext_vector_type(8)));
typedef u16    u16x8  __attribute__((ext_vector_type(8)));
typedef u16    u16x4  __attribute__((ext_vector_type(4)));
typedef float  f32x4  __attribute__((ext_vector_type(4)));

#define BSZ    256
#define NATOMS 128
#define INF    128
#define HH     256
#define H3     768
#define MAXV   6
#define OUTF   256
#define KFC    (HH * MAXV)      // 1536
#define PLANE  8388608          // u16 elems per xp2 gate plane: 16*128*8*64*8
#define HAP    264              // hA row pitch (u16)

__device__ __forceinline__ u16 f2bf(float f) {
  union { float f; unsigned u; } v; v.f = f;
  unsigned u = v.u;
  unsigned r = (u + 0x7FFFu + ((u >> 16) & 1u)) >> 16;  // RNE
  return (u16)r;
}
__device__ __forceinline__ float bf2f(u16 h) {
  union { unsigned u; float f; } v; v.u = ((unsigned)h) << 16;
  return v.f;
}
__device__ __forceinline__ f32x4 mfma_bf16(u16x8 a, u16x8 b, f32x4 c) {
  return __builtin_amdgcn_mfma_f32_16x16x32_bf16(
      __builtin_bit_cast(bf16x8, a), __builtin_bit_cast(bf16x8, b), c, 0, 0, 0);
}
// pick a0..a3 by runtime quad index (registers are not lane-indexable)
__device__ __forceinline__ float sel4(float a0, float a1, float a2, float a3, int q) {
  float t01 = (q & 1) ? a1 : a0;
  float t23 = (q & 1) ? a3 : a2;
  return (q & 2) ? t23 : t01;
}

// ---------------- prep: W_hh and W_fc fp32 -> bf16 ----------------
__global__ void k_prep(const float* __restrict__ whh, u16* __restrict__ whho,
                       const float* __restrict__ wfc, u16* __restrict__ wfco) {
  int i = blockIdx.x * 256 + threadIdx.x;
  if (i < H3 * HH) whho[i] = f2bf(whh[i]);
  if (i < OUTF * KFC) wfco[i] = f2bf(wfc[i]);
}

// ---------------- stage 1: xp2 = x @ W_ih^T + bih (+bhh for r,z gates) ------
// Output layout (3 gate planes, matched to k_gru's lane/wave mapping):
//   plane g, u16 index: ((bb*128 + t)*8 + ww)*512 + L*8 + p*4 + r
//   where b=bb*16+mb, L=(mb>>2)*16+cc, r=mb&3, n = g*256 + ww*32 + p*16 + cc.
__global__ __launch_bounds__(256) void k_xproj(const float* __restrict__ X,
                                               const float* __restrict__ W,
                                               const float* __restrict__ bias,
                                               const float* __restrict__ bhh,
                                               u16* __restrict__ out) {
  __shared__ __align__(16) u16 As[64][40];
  __shared__ __align__(16) u16 Bs[64][40];
  const int m0 = blockIdx.x * 64, n0 = blockIdx.y * 64;
  const int tid = threadIdx.x, lane = tid & 63, wid = tid >> 6;
  const int wm = (wid & 1) * 32, wn = (wid >> 1) * 32;
  const int lrow = tid >> 2, lcol = (tid & 3) * 8;
  const f32x4 zero = {0.f, 0.f, 0.f, 0.f};
  f32x4 acc[2][2];
#pragma unroll
  for (int mi = 0; mi < 2; mi++)
#pragma unroll
    for (int ni = 0; ni < 2; ni++) acc[mi][ni] = zero;

  for (int kk = 0; kk < INF; kk += 32) {
    const float* ap = X + (size_t)(m0 + lrow) * INF + kk + lcol;
    const float* bp = W + (size_t)(n0 + lrow) * INF + kk + lcol;
    u16x8 av, bv;
#pragma unroll
    for (int j = 0; j < 8; j++) { av[j] = f2bf(ap[j]); bv[j] = f2bf(bp[j]); }
    *(u16x8*)&As[lrow][lcol] = av;
    *(u16x8*)&Bs[lrow][lcol] = bv;
    __syncthreads();
    u16x8 afr[2], bfr[2];
#pragma unroll
    for (int mi = 0; mi < 2; mi++)
      afr[mi] = *(const u16x8*)&As[wm + mi * 16 + (lane & 15)][(lane >> 4) * 8];
#pragma unroll
    for (int ni = 0; ni < 2; ni++)
      bfr[ni] = *(const u16x8*)&Bs[wn + ni * 16 + (lane & 15)][(lane >> 4) * 8];
#pragma unroll
    for (int mi = 0; mi < 2; mi++)
#pragma unroll
      for (int ni = 0; ni < 2; ni++) acc[mi][ni] = mfma_bf16(afr[mi], bfr[ni], acc[mi][ni]);
    __syncthreads();
  }
#pragma unroll
  for (int mi = 0; mi < 2; mi++)
#pragma unroll
    for (int ni = 0; ni < 2; ni++) {
      const int n = n0 + wn + ni * 16 + (lane & 15);
      const int g = n >> 8, i2 = n & 255;
      const int ww = i2 >> 5, ii = i2 & 31, pp = ii >> 4, cc = ii & 15;
      const float badd = bias[n] + (g < 2 ? bhh[n] : 0.f);  // fold bhh into r,z
      u16* plane = out + (size_t)g * PLANE;
#pragma unroll
      for (int r = 0; r < 4; r++) {
        const int m = m0 + wm + mi * 16 + (lane >> 4) * 4 + r;  // m = b*128 + t
        const int b = m >> 7, t = m & 127, bb = b >> 4, mb = b & 15;
        const size_t off = ((size_t)((bb * 128 + t) * 8 + ww) << 9) +
                           ((((mb >> 2) << 4) | cc) << 3) + pp * 4 + (mb & 3);
        plane[off] = f2bf(acc[mi][ni][r] + badd);
      }
    }
}

// ---------------- stage 2: GRU recurrence -----------------------------------
// 64 blocks x 256 thr (4 waves), 1 wave/EU => 512 unified regs/wave: the full
// W_hh wave-slice (12 tiles x 8 kfrags = 384 regs) is PINNED IN AGPRS ("+a");
// VGPR working set ~120. R3/R5 spilled because 2 waves/EU caps the UNIFIED
// budget at 256 (pool 512/SIMD), not 256 VGPR + 256 AGPR.
// Block owns 4 batches; A-rows replicate batches (af from row c&3) so every
// quad holds all 4 batches; quad q's gate columns (cb=q) come from the 48
// accumulators via 3-deep cndmask selects.
__global__ void __attribute__((amdgpu_flat_work_group_size(256, 256),
                               amdgpu_waves_per_eu(1, 1)))
k_gru(const u16* __restrict__ Whh, const float* __restrict__ bhh,
      const u16* __restrict__ xp2, u16* __restrict__ rnn) {
  __shared__ __align__(16) u16 hA[2][4 * HAP];   // bf16 h, 4 batch rows, dbuf
  const int tid = threadIdx.x, lane = tid & 63, w = tid >> 6;  // w in [0,4)
  const int c = lane & 15, q = lane >> 4;
  const int b0 = blockIdx.x * 4;
  const int bb = blockIdx.x >> 2;          // 16-batch group (k_xproj layout)
  const int Lq = (blockIdx.x & 3) * 16 + c;

  for (int i = tid; i < 2 * 4 * HAP; i += 256) ((u16*)hA)[i] = 0;

  // W_hh fragments: 12 tiles (nt = g*4 + cb) x 8 k-frags = 384 regs -> AGPR
  u16x8 wf[12][8];
#pragma unroll
  for (int nt = 0; nt < 12; nt++)
#pragma unroll
    for (int kt = 0; kt < 8; kt++) {
      const int n = (nt >> 2) * 256 + w * 64 + (nt & 3) * 16 + c;
      wf[nt][kt] = *(const u16x8*)(Whh + (size_t)n * HH + kt * 32 + q * 8);
    }
#pragma unroll
  for (int nt = 0; nt < 12; nt++)
#pragma unroll
    for (int kt = 0; kt < 8; kt++) asm volatile("" : "+a"(wf[nt][kt]));

  const int col = w * 64 + q * 16 + c;          // this lane's gate column
  const float bhhn = bhh[512 + col];
  float hreg[4] = {0.f, 0.f, 0.f, 0.f};

  // per-thread xp stream: 4 contiguous u16 (batches r=0..3) per plane per step
  const u16* gbase = xp2 + ((size_t)(bb * 128) * 8 + (w * 2 + (q >> 1))) * 512 +
                     (size_t)Lq * 8 + (q & 1) * 4;
  // bulk rnn store mapping: lanes 0..31 of wave w store batch row w
  const int sl = lane & 31;
  u16* rnn_base = rnn + ((size_t)(b0 + w) * NATOMS) * HH + sl * 8;

  u16x4 xgn[3];
#pragma unroll
  for (int g = 0; g < 3; g++) xgn[g] = *(const u16x4*)(gbase + (size_t)g * PLANE);

  __syncthreads();

  const f32x4 zero4 = {0.f, 0.f, 0.f, 0.f};
#pragma unroll 1
  for (int t = 0; t < NATOMS; t++) {
    const u16* hc = hA[t & 1];
    u16* hnx = hA[(t + 1) & 1];

    // bulk store h_{t-1} -> rnn[t-1] (vectorized; replaces 8 scalar stores)
    if (t && lane < 32) {
      const u16x8 hv8 = *(const u16x8*)&hc[w * HAP + sl * 8];
      *(u16x8*)(rnn_base + (size_t)(t - 1) * HH) = hv8;
    }

    // consume prefetched xp, issue next step's loads
    u16x4 xg[3];
#pragma unroll
    for (int g = 0; g < 3; g++) xg[g] = xgn[g];
    if (t < NATOMS - 1) {
      const u16* gp = gbase + (size_t)(t + 1) * 4096;
#pragma unroll
      for (int g = 0; g < 3; g++) xgn[g] = *(const u16x4*)(gp + (size_t)g * PLANE);
    }

    // ---- gh = h @ Whh^T: A rows replicate the 4 batches (row c&3) ----
    f32x4 acc[12];
#pragma unroll
    for (int nt = 0; nt < 12; nt++) acc[nt] = zero4;
#pragma unroll
    for (int kt = 0; kt < 8; kt++) {
      const u16x8 a = *(const u16x8*)&hc[(c & 3) * HAP + kt * 32 + q * 8];
#pragma unroll
      for (int nt = 0; nt < 12; nt++) acc[nt] = mfma_bf16(a, wf[nt][kt], acc[nt]);
    }

    // ---- gates: lane handles (col, batches 0..3); tile cb=q via selects ----
#pragma unroll
    for (int r_ = 0; r_ < 4; r_++) {
      const float Ar = sel4(acc[0][r_], acc[1][r_], acc[2][r_], acc[3][r_], q);
      const float Az = sel4(acc[4][r_], acc[5][r_], acc[6][r_], acc[7][r_], q);
      const float An = sel4(acc[8][r_], acc[9][r_], acc[10][r_], acc[11][r_], q);
      const float ar = Ar + bf2f(xg[0][r_]);   // bih+bhh pre-folded
      const float az = Az + bf2f(xg[1][r_]);
      const float hn = An + bhhn;
      const float xn = bf2f(xg[2][r_]);
      const float rr = 1.f / (1.f + __expf(-ar));
      const float zz = 1.f / (1.f + __expf(-az));
      const float e  = __expf(2.f * (xn + rr * hn));
      const float nn = 1.f - 2.f / (e + 1.f);
      const float hv = nn + zz * (hreg[r_] - nn);
      hreg[r_] = hv;
      hnx[r_ * HAP + col] = f2bf(hv);
    }
    __syncthreads();
  }
  // final store: h_127 lives in hA[0]
  if (lane < 32) {
    const u16x8 hv8 = *(const u16x8*)&hA[0][w * HAP + sl * 8];
    *(u16x8*)(rnn_base + (size_t)(NATOMS - 1) * HH) = hv8;
  }
}

// ---------------- stage 3: out = leaky(gather(rnn) @ W_fc^T + b_fc) ---------
__global__ __launch_bounds__(256) void k_fc(const u16* __restrict__ rnn,
                                            const int* __restrict__ bonded,
                                            const u16* __restrict__ W,
                                            const float* __restrict__ bias,
                                            float* __restrict__ out) {
  __shared__ __align__(16) u16 As[64][40];
  __shared__ __align__(16) u16 Bs[64][40];
  const int m0 = blockIdx.x * 64, n0 = blockIdx.y * 64;
  const int tid = threadIdx.x, lane = tid & 63, wid = tid >> 6;
  const int wm = (wid & 1) * 32, wn = (wid >> 1) * 32;
  const int lrow = tid >> 2, lcol = (tid & 3) * 8;
  const int m = m0 + lrow;
  const int b = m >> 7, atom = m & 127;
  const int* bptr = bonded + (size_t)(b * NATOMS + atom) * MAXV;
  const f32x4 zero = {0.f, 0.f, 0.f, 0.f};
  f32x4 acc[2][2];
#pragma unroll
  for (int mi = 0; mi < 2; mi++)
#pragma unroll
    for (int ni = 0; ni < 2; ni++) acc[mi][ni] = zero;

  for (int kk = 0; kk < KFC; kk += 32) {
    int k = kk + lcol;
    int v = k >> 8, kr = k & 255;
    int idx = bptr[v];
    u16x8 av = *(const u16x8*)(rnn + (size_t)(b * NATOMS + idx) * HH + kr);
    u16x8 bv = *(const u16x8*)(W + (size_t)(n0 + lrow) * KFC + k);
    *(u16x8*)&As[lrow][lcol] = av;
    *(u16x8*)&Bs[lrow][lcol] = bv;
    __syncthreads();
    u16x8 afr[2], bfr[2];
#pragma unroll
    for (int mi = 0; mi < 2; mi++)
      afr[mi] = *(const u16x8*)&As[wm + mi * 16 + (lane & 15)][(lane >> 4) * 8];
#pragma unroll
    for (int ni = 0; ni < 2; ni++)
      bfr[ni] = *(const u16x8*)&Bs[wn + ni * 16 + (lane & 15)][(lane >> 4) * 8];
#pragma unroll
    for (int mi = 0; mi < 2; mi++)
#pragma unroll
      for (int ni = 0; ni < 2; ni++) acc[mi][ni] = mfma_bf16(afr[mi], bfr[ni], acc[mi][ni]);
    __syncthreads();
  }
#pragma unroll
  for (int mi = 0; mi < 2; mi++)
#pragma unroll
    for (int ni = 0; ni < 2; ni++) {
      int n = n0 + wn + ni * 16 + (lane & 15);
      float bv = bias[n];
#pragma unroll
      for (int r = 0; r < 4; r++) {
        int mm = m0 + wm + mi * 16 + (lane >> 4) * 4 + r;
        float vv = acc[mi][ni][r] + bv;
        out[(size_t)mm * OUTF + n] = vv >= 0.f ? vv : 0.1f * vv;
      }
    }
}

extern "C" void kernel_launch(void* const* d_in, const int* in_sizes, int n_in,
                              void* d_out, int out_size, void* d_ws, size_t ws_size,
                              hipStream_t stream) {
  const float* x      = (const float*)d_in[0];
  const int*   bonded = (const int*)d_in[1];
  const float* Wih    = (const float*)d_in[2];
  const float* Whh    = (const float*)d_in[3];
  const float* bih    = (const float*)d_in[4];
  const float* bhh    = (const float*)d_in[5];
  const float* Wfc    = (const float*)d_in[6];
  const float* bfc    = (const float*)d_in[7];
  float* out = (float*)d_out;

  char* ws = (char*)d_ws;
  u16* xp2  = (u16*)(ws);                                    // 50,331,648 B
  u16* rnn  = (u16*)(ws + 50331648);                         // 16,777,216 B
  u16* whhb = (u16*)(ws + 50331648 + 16777216);              //    393,216 B
  u16* wfcb = (u16*)(ws + 50331648 + 16777216 + 393216);     //    786,432 B

  k_prep<<<(OUTF * KFC + 255) / 256, 256, 0, stream>>>(Whh, whhb, Wfc, wfcb);
  k_xproj<<<dim3(512, 12), 256, 0, stream>>>(x, Wih, bih, bhh, xp2);
  k_gru<<<64, 256, 0, stream>>>(whhb, bhh, xp2, rnn);
  k_fc<<<dim3(512, 4), 256, 0, stream>>>(rnn, bonded, wfcb, bfc, out);
}

// Round 7
// 365.663 us; speedup vs baseline: 1.8738x; 1.1848x over previous
//
#include <hip/hip_runtime.h>
#include <hip/hip_bf16.h>
#include <stdint.h>

typedef unsigned short u16;
typedef __bf16 bf16_t;
typedef bf16_t bf16x8 __attribute__((ext_vector_type(8)));
typedef u16    u16x8  __attribute__((ext_vector_type(8)));
typedef u16    u16x4  __attribute__((ext_vector_type(4)));
typedef float  f32x4  __attribute__((ext_vector_type(4)));

#define BSZ    256
#define NATOMS 128
#define INF    128
#define HH     256
#define H3     768
#define MAXV   6
#define OUTF   256
#define KFC    (HH * MAXV)      // 1536
#define PLANE  8388608          // u16 elems per xp2 gate plane
#define HAP    264              // hA row pitch (u16)

__device__ __forceinline__ u16 f2bf(float f) {
  union { float f; unsigned u; } v; v.f = f;
  unsigned u = v.u;
  unsigned r = (u + 0x7FFFu + ((u >> 16) & 1u)) >> 16;  // RNE
  return (u16)r;
}
__device__ __forceinline__ float bf2f(u16 h) {
  union { unsigned u; float f; } v; v.u = ((unsigned)h) << 16;
  return v.f;
}
__device__ __forceinline__ f32x4 mfma_bf16(u16x8 a, u16x8 b, f32x4 c) {
  return __builtin_amdgcn_mfma_f32_16x16x32_bf16(
      __builtin_bit_cast(bf16x8, a), __builtin_bit_cast(bf16x8, b), c, 0, 0, 0);
}
__device__ __forceinline__ float sel4(float a0, float a1, float a2, float a3, int q) {
  float t01 = (q & 1) ? a1 : a0;
  float t23 = (q & 1) ? a3 : a2;
  return (q & 2) ? t23 : t01;
}

// ---------------- prep: x, W_ih, W_hh, W_fc fp32 -> bf16 (float4 vectorized) --
#define NX4   1048576
#define C1    1048576
#define C2    1073152
#define C3    1122304
#define C4    1220608
__global__ void k_prep4(const float* __restrict__ x, const float* __restrict__ wih,
                        const float* __restrict__ whh, const float* __restrict__ wfc,
                        u16* __restrict__ xb, u16* __restrict__ wihb,
                        u16* __restrict__ whhb, u16* __restrict__ wfcb) {
  int i = blockIdx.x * 256 + threadIdx.x;
  const float* src; u16* dst; int j;
  if (i < C1)      { src = x;   dst = xb;   j = i; }
  else if (i < C2) { src = wih; dst = wihb; j = i - C1; }
  else if (i < C3) { src = whh; dst = whhb; j = i - C2; }
  else             { src = wfc; dst = wfcb; j = i - C3; }
  f32x4 v = *(const f32x4*)(src + (size_t)j * 4);
  u16x4 o;
#pragma unroll
  for (int k = 0; k < 4; k++) o[k] = f2bf(v[k]);
  *(u16x4*)(dst + (size_t)j * 4) = o;
}

// ---------------- stage 1: xp2 = x @ W_ih^T + biases (128x128 tile, BK=128) --
// M-tiles are INTERLEAVED: LDS row L <-> (batch bg*4 + (L&3), t = tg*32 + (L>>2)),
// so a thread's 4 C-values (quad*4+r_) are 4 consecutive BATCHES at fixed t ->
// one 8B u16x4 store into xp2's r-innermost quartet (vs 64 scalar stores in R6).
__global__ __launch_bounds__(256) void k_xproj(const u16* __restrict__ X,
                                               const u16* __restrict__ W,
                                               const float* __restrict__ bias,
                                               const float* __restrict__ bhh,
                                               u16* __restrict__ out) {
  __shared__ __align__(16) u16 As[128][136];  // pitch 272B = 17*16 (aligned, 2-way banks)
  __shared__ __align__(16) u16 Bs[128][136];
  const int tid = threadIdx.x, lane = tid & 63, wid = tid >> 6;
  const int c16 = lane & 15, quad = lane >> 4;
  const int wm = (wid & 1) * 64, wn = (wid >> 1) * 64;
  const int bg = blockIdx.x >> 2, tg = blockIdx.x & 3;
  const int n0 = blockIdx.y * 128;

  // stage A (interleaved rows) and B
#pragma unroll
  for (int j = 0; j < 8; j++) {
    const int u = tid + j * 256, row = u >> 4, ch = u & 15;
    const int b = bg * 4 + (row & 3), t = tg * 32 + (row >> 2);
    *(u16x8*)&As[row][ch * 8] =
        *(const u16x8*)(X + ((size_t)b * 16384 + t * 128 + ch * 8));
    *(u16x8*)&Bs[row][ch * 8] =
        *(const u16x8*)(W + ((size_t)(n0 + row) * 128 + ch * 8));
  }
  __syncthreads();

  const f32x4 zero = {0.f, 0.f, 0.f, 0.f};
  f32x4 acc[4][4];
#pragma unroll
  for (int mi = 0; mi < 4; mi++)
#pragma unroll
    for (int ni = 0; ni < 4; ni++) acc[mi][ni] = zero;

#pragma unroll
  for (int kt = 0; kt < 4; kt++) {
    u16x8 af[4], bf[4];
#pragma unroll
    for (int mi = 0; mi < 4; mi++)
      af[mi] = *(const u16x8*)&As[wm + mi * 16 + c16][kt * 32 + quad * 8];
#pragma unroll
    for (int ni = 0; ni < 4; ni++)
      bf[ni] = *(const u16x8*)&Bs[wn + ni * 16 + c16][kt * 32 + quad * 8];
#pragma unroll
    for (int mi = 0; mi < 4; mi++)
#pragma unroll
      for (int ni = 0; ni < 4; ni++)
        acc[mi][ni] = mfma_bf16(af[mi], bf[ni], acc[mi][ni]);
  }

  // epilogue: u16x4 store per (mi,ni) — 4 batches r_=0..3 at fixed (t, n)
  const int bb = bg >> 2, mbh = bg & 3;
#pragma unroll
  for (int ni = 0; ni < 4; ni++) {
    const int n = n0 + wn + ni * 16 + c16;
    const int g = n >> 8, ww = (n >> 5) & 7, pp = (n >> 4) & 1, cc = n & 15;
    const float badd = bias[n] + (g < 2 ? bhh[n] : 0.f);  // fold bhh into r,z
    u16* plane = out + (size_t)g * PLANE;
#pragma unroll
    for (int mi = 0; mi < 4; mi++) {
      const int t = tg * 32 + (wm >> 2) + mi * 4 + quad;
      u16x4 sv;
#pragma unroll
      for (int r_ = 0; r_ < 4; r_++) sv[r_] = f2bf(acc[mi][ni][r_] + badd);
      *(u16x4*)(plane + (((size_t)((bb * 128 + t) * 8 + ww)) << 9) +
                (mbh * 16 + cc) * 8 + pp * 4) = sv;
    }
  }
}

// ---------------- stage 2: GRU recurrence (UNCHANGED from R6 — control) -----
__global__ void __attribute__((amdgpu_flat_work_group_size(256, 256),
                               amdgpu_waves_per_eu(1, 1)))
k_gru(const u16* __restrict__ Whh, const float* __restrict__ bhh,
      const u16* __restrict__ xp2, u16* __restrict__ rnn) {
  __shared__ __align__(16) u16 hA[2][4 * HAP];
  const int tid = threadIdx.x, lane = tid & 63, w = tid >> 6;
  const int c = lane & 15, q = lane >> 4;
  const int b0 = blockIdx.x * 4;
  const int bb = blockIdx.x >> 2;
  const int Lq = (blockIdx.x & 3) * 16 + c;

  for (int i = tid; i < 2 * 4 * HAP; i += 256) ((u16*)hA)[i] = 0;

  u16x8 wf[12][8];
#pragma unroll
  for (int nt = 0; nt < 12; nt++)
#pragma unroll
    for (int kt = 0; kt < 8; kt++) {
      const int n = (nt >> 2) * 256 + w * 64 + (nt & 3) * 16 + c;
      wf[nt][kt] = *(const u16x8*)(Whh + (size_t)n * HH + kt * 32 + q * 8);
    }
#pragma unroll
  for (int nt = 0; nt < 12; nt++)
#pragma unroll
    for (int kt = 0; kt < 8; kt++) asm volatile("" : "+a"(wf[nt][kt]));

  const int col = w * 64 + q * 16 + c;
  const float bhhn = bhh[512 + col];
  float hreg[4] = {0.f, 0.f, 0.f, 0.f};

  const u16* gbase = xp2 + ((size_t)(bb * 128) * 8 + (w * 2 + (q >> 1))) * 512 +
                     (size_t)Lq * 8 + (q & 1) * 4;
  const int sl = lane & 31;
  u16* rnn_base = rnn + ((size_t)(b0 + w) * NATOMS) * HH + sl * 8;

  u16x4 xgn[3];
#pragma unroll
  for (int g = 0; g < 3; g++) xgn[g] = *(const u16x4*)(gbase + (size_t)g * PLANE);

  __syncthreads();

  const f32x4 zero4 = {0.f, 0.f, 0.f, 0.f};
#pragma unroll 1
  for (int t = 0; t < NATOMS; t++) {
    const u16* hc = hA[t & 1];
    u16* hnx = hA[(t + 1) & 1];

    if (t && lane < 32) {
      const u16x8 hv8 = *(const u16x8*)&hc[w * HAP + sl * 8];
      *(u16x8*)(rnn_base + (size_t)(t - 1) * HH) = hv8;
    }

    u16x4 xg[3];
#pragma unroll
    for (int g = 0; g < 3; g++) xg[g] = xgn[g];
    if (t < NATOMS - 1) {
      const u16* gp = gbase + (size_t)(t + 1) * 4096;
#pragma unroll
      for (int g = 0; g < 3; g++) xgn[g] = *(const u16x4*)(gp + (size_t)g * PLANE);
    }

    f32x4 acc[12];
#pragma unroll
    for (int nt = 0; nt < 12; nt++) acc[nt] = zero4;
#pragma unroll
    for (int kt = 0; kt < 8; kt++) {
      const u16x8 a = *(const u16x8*)&hc[(c & 3) * HAP + kt * 32 + q * 8];
#pragma unroll
      for (int nt = 0; nt < 12; nt++) acc[nt] = mfma_bf16(a, wf[nt][kt], acc[nt]);
    }

#pragma unroll
    for (int r_ = 0; r_ < 4; r_++) {
      const float Ar = sel4(acc[0][r_], acc[1][r_], acc[2][r_], acc[3][r_], q);
      const float Az = sel4(acc[4][r_], acc[5][r_], acc[6][r_], acc[7][r_], q);
      const float An = sel4(acc[8][r_], acc[9][r_], acc[10][r_], acc[11][r_], q);
      const float ar = Ar + bf2f(xg[0][r_]);
      const float az = Az + bf2f(xg[1][r_]);
      const float hn = An + bhhn;
      const float xn = bf2f(xg[2][r_]);
      const float rr = 1.f / (1.f + __expf(-ar));
      const float zz = 1.f / (1.f + __expf(-az));
      const float e  = __expf(2.f * (xn + rr * hn));
      const float nn = 1.f - 2.f / (e + 1.f);
      const float hv = nn + zz * (hreg[r_] - nn);
      hreg[r_] = hv;
      hnx[r_ * HAP + col] = f2bf(hv);
    }
    __syncthreads();
  }
  if (lane < 32) {
    const u16x8 hv8 = *(const u16x8*)&hA[0][w * HAP + sl * 8];
    *(u16x8*)(rnn_base + (size_t)(NATOMS - 1) * HH) = hv8;
  }
}

// ---------------- stage 3: out = leaky(gather(rnn) @ W_fc^T + b_fc) ---------
// 128x128 tile, BK=64, one batch per block (m0 = bx*128). Operand roles are
// SWAPPED (W_fc rows = MFMA-M, atoms = MFMA-N) so a thread's D-fragment holds
// 4 consecutive n -> float4 epilogue stores (vs 64 scalar stores).
__global__ __launch_bounds__(256) void k_fc(const u16* __restrict__ rnn,
                                            const int* __restrict__ bonded,
                                            const u16* __restrict__ W,
                                            const float* __restrict__ bias,
                                            float* __restrict__ out) {
  __shared__ __align__(16) u16 As[128][72];   // gathered rnn rows (atoms)
  __shared__ __align__(16) u16 Bs[128][72];   // W_fc rows
  __shared__ int ic[128][6];
  const int tid = threadIdx.x, lane = tid & 63, wid = tid >> 6;
  const int c16 = lane & 15, quad = lane >> 4;
  const int wNm = (wid & 1) * 64;   // W-row side (MFMA-M)
  const int wNa = (wid >> 1) * 64;  // atom side (MFMA-N)
  const int bx = blockIdx.x, n0 = blockIdx.y * 128;

  for (int u = tid; u < 768; u += 256) {
    const int v = u >> 7, row = u & 127;
    ic[row][v] = bonded[(size_t)(bx * 128 + row) * MAXV + v];
  }
  __syncthreads();

  const f32x4 zero = {0.f, 0.f, 0.f, 0.f};
  f32x4 acc[4][4];
#pragma unroll
  for (int mi = 0; mi < 4; mi++)
#pragma unroll
    for (int ni = 0; ni < 4; ni++) acc[mi][ni] = zero;

  for (int it = 0; it < 24; it++) {
    const int kk = it * 64, v = kk >> 8, kr = kk & 255;
#pragma unroll
    for (int j = 0; j < 4; j++) {
      const int u = tid + j * 256, row = u >> 3, ch = u & 7;
      const int idx = ic[row][v];
      *(u16x8*)&As[row][ch * 8] =
          *(const u16x8*)(rnn + ((size_t)(bx * 128 + idx)) * HH + kr + ch * 8);
      *(u16x8*)&Bs[row][ch * 8] =
          *(const u16x8*)(W + (size_t)(n0 + row) * KFC + kk + ch * 8);
    }
    __syncthreads();
#pragma unroll
    for (int kt = 0; kt < 2; kt++) {
      u16x8 aw[4], ba[4];
#pragma unroll
      for (int mi = 0; mi < 4; mi++)
        aw[mi] = *(const u16x8*)&Bs[wNm + mi * 16 + c16][kt * 32 + quad * 8];
#pragma unroll
      for (int ni = 0; ni < 4; ni++)
        ba[ni] = *(const u16x8*)&As[wNa + ni * 16 + c16][kt * 32 + quad * 8];
#pragma unroll
      for (int mi = 0; mi < 4; mi++)
#pragma unroll
        for (int ni = 0; ni < 4; ni++)
          acc[mi][ni] = mfma_bf16(aw[mi], ba[ni], acc[mi][ni]);
    }
    __syncthreads();
  }

  // epilogue: D[row=W-row][col=atom]; float4 over 4 consecutive n
#pragma unroll
  for (int mi = 0; mi < 4; mi++) {
    const int n = n0 + wNm + mi * 16 + quad * 4;
    const f32x4 bv = *(const f32x4*)(bias + n);
#pragma unroll
    for (int ni = 0; ni < 4; ni++) {
      const int mm = bx * 128 + wNa + ni * 16 + c16;
      f32x4 vv;
#pragma unroll
      for (int r_ = 0; r_ < 4; r_++) {
        const float t = acc[mi][ni][r_] + bv[r_];
        vv[r_] = t >= 0.f ? t : 0.1f * t;
      }
      *(f32x4*)(out + (size_t)mm * OUTF + n) = vv;
    }
  }
}

extern "C" void kernel_launch(void* const* d_in, const int* in_sizes, int n_in,
                              void* d_out, int out_size, void* d_ws, size_t ws_size,
                              hipStream_t stream) {
  const float* x      = (const float*)d_in[0];
  const int*   bonded = (const int*)d_in[1];
  const float* Wih    = (const float*)d_in[2];
  const float* Whh    = (const float*)d_in[3];
  const float* bih    = (const float*)d_in[4];
  const float* bhh    = (const float*)d_in[5];
  const float* Wfc    = (const float*)d_in[6];
  const float* bfc    = (const float*)d_in[7];
  float* out = (float*)d_out;

  char* ws = (char*)d_ws;
  u16* xp2  = (u16*)(ws);                       // 50,331,648 B
  u16* rnn  = (u16*)(ws + 50331648);            // 16,777,216 B
  u16* whhb = (u16*)(ws + 67108864);            //    393,216 B
  u16* wfcb = (u16*)(ws + 67502080);            //    786,432 B
  u16* xb   = (u16*)(ws + 68288512);            //  8,388,608 B
  u16* wihb = (u16*)(ws + 76677120);            //    196,608 B

  k_prep4<<<C4 / 256, 256, 0, stream>>>(x, Wih, Whh, Wfc, xb, wihb, whhb, wfcb);
  k_xproj<<<dim3(256, 6), 256, 0, stream>>>(xb, wihb, bih, bhh, xp2);
  k_gru<<<64, 256, 0, stream>>>(whhb, bhh, xp2, rnn);
  k_fc<<<dim3(256, 2), 256, 0, stream>>>(rnn, bonded, wfcb, bfc, out);
}